// Round 2
// baseline (64.555 us; speedup 1.0000x reference)
//
#include <hip/hip_runtime.h>
#include <math.h>

#define NN 256
#define DD 256
#define KK 16
#define M_MARGIN 0.6f
#define T_THRESH 0.0025f
#define EPS 1e-12f

// Block i handles row i with 1024 threads: 4 lanes (s = t&3) share candidate
// j = t>>2, splitting the D-loop four ways; partials combine via 2 __shfl_xor
// steps. Two-pass trick: pass 1 computes only q = y_j.y_i, nn = y_j.y_j and
// uu = y_i.y_i (folding the row-i norm into the loop kills the whole norm
// phase + its LDS round-trip, and halves D-loop LDS traffic by not touching
// s_yit). After ranking, only the <=16 neighbor groups run pass 2 (qt, vv,
// cross) under exec-mask — negligible cost. Gram identity
// ||a_i - a_j||^2 = 2 - 2*(y_i.y_j)/(n_i*n_j) as before.
__global__ void __launch_bounds__(1024) blcd_row_kernel(
    const float* __restrict__ yi, const float* __restrict__ yit,
    float* __restrict__ partial)
{
    __shared__ float s_yi[DD];    // raw row i
    __shared__ float s_yit[DD];   // raw row i (tilde) — read only by pass 2
    __shared__ float sdis[NN];    // dis_yii[i][:]
    __shared__ float red[16];     // wave partials for final reduce

    const int i = blockIdx.x;
    const int t = threadIdx.x;    // 0..1023
    const int j = t >> 2;         // candidate row 0..255
    const int s = t & 3;          // quarter of the D-range
    const int w = t >> 6;         // wave id 0..15

    // Stage row i (+tilde). No norm phase — norms fold into pass 1 / pass 2.
    if (t < DD) {
        s_yi[t]  = yi [i * DD + t];
        s_yit[t] = yit[i * DD + t];
    }

    // Prefetch this lane's quarter of row j: d4 = 4k + s. Lanes 4g..4g+3 read
    // 4 adjacent float4 (64B contiguous) — fully coalesced.
    const float4* __restrict__ rj = (const float4*)(yi + j * DD);
    float4 p[16];
    #pragma unroll
    for (int k = 0; k < 16; ++k) p[k] = rj[4 * k + s];

    __syncthreads();

    // Pass 1: q = y_j.u, nn = y_j.y_j, uu = u.u  (u = row i from LDS).
    const float4* __restrict__ si = (const float4*)s_yi;
    float4 q4  = make_float4(0.f, 0.f, 0.f, 0.f);
    float4 nn4 = make_float4(0.f, 0.f, 0.f, 0.f);
    float4 uu4 = make_float4(0.f, 0.f, 0.f, 0.f);
    #pragma unroll
    for (int k = 0; k < 16; ++k) {
        const float4 y = p[k];
        const float4 u = si[4 * k + s];
        q4.x  += y.x * u.x; q4.y  += y.y * u.y; q4.z  += y.z * u.z; q4.w  += y.w * u.w;
        nn4.x += y.x * y.x; nn4.y += y.y * y.y; nn4.z += y.z * y.z; nn4.w += y.w * y.w;
        uu4.x += u.x * u.x; uu4.y += u.y * u.y; uu4.z += u.z * u.z; uu4.w += u.w * u.w;
    }
    float q  = (q4.x  + q4.y ) + (q4.z  + q4.w );
    float nn = (nn4.x + nn4.y) + (nn4.z + nn4.w);
    float uu = (uu4.x + uu4.y) + (uu4.z + uu4.w);
    // Combine the four quarters (lanes s^1, s^2 are in the same wave).
    q  += __shfl_xor(q,  1, 64);  q  += __shfl_xor(q,  2, 64);
    nn += __shfl_xor(nn, 1, 64);  nn += __shfl_xor(nn, 2, 64);
    uu += __shfl_xor(uu, 1, 64);  uu += __shfl_xor(uu, 2, 64);

    const float inv_ni = 1.0f / sqrtf(uu + EPS);
    const float inv_nt = 1.0f / sqrtf(nn + EPS);
    const float c   = q * inv_nt * inv_ni;
    const float myv = 0.5f * sqrtf(fmaxf(2.0f - 2.0f * c, 0.0f) + EPS);
    if (s == 0) sdis[j] = myv;
    __syncthreads();

    // Stable rank == top_k position (ties -> lower index first), 4-way split.
    // k = 4m + s keeps the four lanes' reads 16B apart -> conflict-free.
    int rank = 0;
    const float4* sd4 = (const float4*)sdis;
    #pragma unroll
    for (int m = 0; m < 16; ++m) {
        const int k = 4 * m + s;
        float4 v = sd4[k];
        const int jj = k * 4;
        rank += (v.x < myv || (v.x == myv && (jj + 0) < j)) ? 1 : 0;
        rank += (v.y < myv || (v.y == myv && (jj + 1) < j)) ? 1 : 0;
        rank += (v.z < myv || (v.z == myv && (jj + 2) < j)) ? 1 : 0;
        rank += (v.w < myv || (v.w == myv && (jj + 3) < j)) ? 1 : 0;
    }
    rank += __shfl_xor(rank, 1, 64);
    rank += __shfl_xor(rank, 2, 64);

    // Pass 2: only neighbor groups (rank 1..16) touch the tilde row.
    float contrib = 0.0f;
    if (rank >= 1 && rank <= KK) {
        const float4* __restrict__ sit = (const float4*)s_yit;
        float4 qt4 = make_float4(0.f, 0.f, 0.f, 0.f);
        float4 vv4 = make_float4(0.f, 0.f, 0.f, 0.f);
        float4 uv4 = make_float4(0.f, 0.f, 0.f, 0.f);
        #pragma unroll
        for (int k = 0; k < 16; ++k) {
            const float4 y = p[k];
            const float4 u = si [4 * k + s];
            const float4 v = sit[4 * k + s];
            qt4.x += y.x * v.x; qt4.y += y.y * v.y; qt4.z += y.z * v.z; qt4.w += y.w * v.w;
            vv4.x += v.x * v.x; vv4.y += v.y * v.y; vv4.z += v.z * v.z; vv4.w += v.w * v.w;
            uv4.x += u.x * v.x; uv4.y += u.y * v.y; uv4.z += u.z * v.z; uv4.w += u.w * v.w;
        }
        float qt = (qt4.x + qt4.y) + (qt4.z + qt4.w);
        float vv = (vv4.x + vv4.y) + (vv4.z + vv4.w);
        float uv = (uv4.x + uv4.y) + (uv4.z + uv4.w);
        // All 4 lanes of the group share rank -> all active for the shuffles.
        qt += __shfl_xor(qt, 1, 64);  qt += __shfl_xor(qt, 2, 64);
        vv += __shfl_xor(vv, 1, 64);  vv += __shfl_xor(vv, 2, 64);
        uv += __shfl_xor(uv, 1, 64);  uv += __shfl_xor(uv, 2, 64);

        const float inv_nit = 1.0f / sqrtf(vv + EPS);
        const float ct   = qt * inv_nt * inv_nit;
        const float myvt = 0.5f * sqrtf(fmaxf(2.0f - 2.0f * ct, 0.0f) + EPS);
        if (s == 0) {
            const float dd = myv - myvt;
            contrib = dd * dd - T_THRESH;            // e1 term
            if (rank == 1) {                         // e2 hinge: j is 2nd-NN
                const float cc = uv * inv_ni * inv_nit;
                const float d_iit = 0.5f * sqrtf(fmaxf(2.0f - 2.0f * cc, 0.0f) + EPS);
                contrib += fmaxf(d_iit + M_MARGIN - myv, 0.0f);
            }
        }
    }

    // Block reduce (16 waves) -> one plain store per block (no atomics).
    #pragma unroll
    for (int off = 32; off > 0; off >>= 1) contrib += __shfl_down(contrib, off, 64);
    if ((t & 63) == 0) red[w] = contrib;
    __syncthreads();
    if (t == 0) {
        float tot = ((red[0]  + red[1])  + (red[2]  + red[3]))
                  + ((red[4]  + red[5])  + (red[6]  + red[7]))
                  + ((red[8]  + red[9])  + (red[10] + red[11]))
                  + ((red[12] + red[13]) + (red[14] + red[15]));
        partial[i] = tot;
    }
}

// 256 partials -> scalar. One wave, shuffle-only, no LDS, no barrier.
__global__ void __launch_bounds__(64) blcd_reduce_kernel(
    const float* __restrict__ partial, float* __restrict__ out)
{
    const int t = threadIdx.x;
    const float4 v4 = ((const float4*)partial)[t];   // 64 lanes x 4 = 256
    float v = (v4.x + v4.y) + (v4.z + v4.w);
    #pragma unroll
    for (int off = 32; off > 0; off >>= 1) v += __shfl_down(v, off, 64);
    if (t == 0) out[0] = v;
}

extern "C" void kernel_launch(void* const* d_in, const int* in_sizes, int n_in,
                              void* d_out, int out_size, void* d_ws, size_t ws_size,
                              hipStream_t stream) {
    (void)in_sizes; (void)n_in; (void)out_size; (void)ws_size;

    const float* yi  = (const float*)d_in[0];
    const float* yit = (const float*)d_in[1];
    float* out = (float*)d_out;
    float* ws  = (float*)d_ws;

    blcd_row_kernel<<<NN, 1024, 0, stream>>>(yi, yit, ws);
    blcd_reduce_kernel<<<1, 64, 0, stream>>>(ws, out);
}